// Round 3
// baseline (332.940 us; speedup 1.0000x reference)
//
#include <hip/hip_runtime.h>
#include <hip/hip_bf16.h>
#include <math.h>

// Problem dims (fixed by the reference)
#define M_DIM 16384
#define N_DIM 2048
#define K_DIM 2048
#define BM 128
#define BN 128
#define BKB 128  // K-tile in BYTES (128 int8) -> 16KB tiles
#define NT (K_DIM / BKB)  // 16 K-iterations

typedef __attribute__((ext_vector_type(4))) int i32x4;    // MFMA i8 A/B (16 int8) and C/D
typedef __attribute__((ext_vector_type(8))) char char8;   // 8B int8 store

// ---------- pre-pass 1: per-row signed-pow + int8 quantize ----------
__global__ __launch_bounds__(256) void quant_x_kernel(const float* __restrict__ x,
                                                      const float* __restrict__ alpha,
                                                      char* __restrict__ xq,
                                                      float* __restrict__ s_a) {
  __shared__ float wmax[4];
  const int row = blockIdx.x;
  const int tid = threadIdx.x;
  const size_t base = (size_t)row * K_DIM + tid * 8;
  const float a = alpha[0];
  const float4* xp = (const float4*)(x + base);
  float4 v0 = xp[0];
  float4 v1 = xp[1];
  float v[8] = {v0.x, v0.y, v0.z, v0.w, v1.x, v1.y, v1.z, v1.w};
  if (a == 0.5f) {
#pragma unroll
    for (int i = 0; i < 8; ++i) v[i] = copysignf(sqrtf(fabsf(v[i])), v[i]);
  } else {
#pragma unroll
    for (int i = 0; i < 8; ++i) v[i] = copysignf(powf(fabsf(v[i]), a), v[i]);
  }
  float m = 0.f;
#pragma unroll
  for (int i = 0; i < 8; ++i) m = fmaxf(m, fabsf(v[i]));
#pragma unroll
  for (int off = 32; off > 0; off >>= 1) m = fmaxf(m, __shfl_down(m, off));
  if ((tid & 63) == 0) wmax[tid >> 6] = m;
  __syncthreads();
  float rowmax = fmaxf(fmaxf(wmax[0], wmax[1]), fmaxf(wmax[2], wmax[3]));
  float inv, s;
  if (rowmax > 0.f) { inv = 127.0f / rowmax; s = rowmax * (1.0f / 127.0f); }
  else { inv = 0.f; s = 0.f; }
  char8 q;
#pragma unroll
  for (int i = 0; i < 8; ++i) {
    int qi = (int)__builtin_rintf(v[i] * inv);
    qi = qi > 127 ? 127 : (qi < -127 ? -127 : qi);
    q[i] = (char)qi;
  }
  *(char8*)(xq + base) = q;
  if (tid == 0) s_a[row] = s;
}

// ---------- pre-pass 2: codebook gather -> int8, per-tensor scale ----------
__global__ __launch_bounds__(256) void quant_w_kernel(const int* __restrict__ Wq,
                                                      const float* __restrict__ cent,
                                                      char* __restrict__ wq8,
                                                      float* __restrict__ s_w) {
  __shared__ char cb[16];
  const int tid = threadIdx.x;
  float cmax = 0.f;
#pragma unroll
  for (int j = 0; j < 16; ++j) cmax = fmaxf(cmax, fabsf(cent[j]));
  const float invw = 127.0f / cmax;
  if (tid < 16) cb[tid] = (char)__builtin_rintf(cent[tid] * invw);
  __syncthreads();
  const size_t base = ((size_t)blockIdx.x * 256u + tid) * 8u;
  const int4* qp = (const int4*)(Wq + base);
  int4 q0 = qp[0], q1 = qp[1];
  char8 r;
  r[0] = cb[q0.x]; r[1] = cb[q0.y]; r[2] = cb[q0.z]; r[3] = cb[q0.w];
  r[4] = cb[q1.x]; r[5] = cb[q1.y]; r[6] = cb[q1.z]; r[7] = cb[q1.w];
  *(char8*)(wq8 + base) = r;
  if (blockIdx.x == 0 && tid == 0) s_w[0] = cmax * (1.0f / 127.0f);
}

// ---------- GEMM: int8, register-double-buffered staging ----------
// Tile k+1 is prefetched global->VGPR (plain dwordx4) BEFORE the compute phase of
// tile k, so the barrier's vmcnt(0) drain is ~free (loads land during compute).
// ds_write_b128 between the two barriers puts it in LDS (XOR-swizzled phys groups,
// permuted-contiguous per inst -> conflict-free). Single 32KB LDS buffer.
__global__ __launch_bounds__(256) void gemm_i8_kernel(const unsigned char* __restrict__ A,
                                                      const unsigned char* __restrict__ B,
                                                      float* __restrict__ C,
                                                      const float* __restrict__ alpha,
                                                      const float* __restrict__ s_a,
                                                      const float* __restrict__ s_w) {
  __shared__ unsigned char As[BM * BKB];  // 16 KB
  __shared__ unsigned char Bs[BN * BKB];  // 16 KB

  const int tid  = threadIdx.x;
  const int wave = tid >> 6;
  const int lane = tid & 63;

  // 16x16 super-tile block swizzle (L2 locality)
  const int bid    = blockIdx.x;          // 0..2047
  const int st     = bid >> 8;
  const int within = bid & 255;
  const int m0 = (st * 16 + (within & 15)) * BM;
  const int n0 = (within >> 4) * BN;

  const int wm   = wave >> 1;
  const int wn   = wave & 1;
  const int r    = lane & 15;
  const int quad = lane >> 4;

  // staging: thread covers rows {j*32 + wave*8 + lane/8 : j=0..3} of A and B,
  // loads logical 16B group (lane&7), writes LDS phys group (lane&7)^(row&7).
  const int srow = wave * 8 + (lane >> 3);
  const int glog = lane & 7;
  const int pgrp = glog ^ (lane >> 3);    // XOR swizzle (row&7 == lane>>3)
  const unsigned char* aP = A + (size_t)(m0 + srow) * K_DIM + glog * 16;
  const unsigned char* bP = B + (size_t)(n0 + srow) * K_DIM + glog * 16;
  const int ldsOff = srow * BKB + pgrp * 16;

  i32x4 pfa[4], pfb[4];  // prefetch registers (32 VGPRs)
#define LOAD_TILES(k0)                                                        \
  do {                                                                        \
    _Pragma("unroll")                                                         \
    for (int j = 0; j < 4; ++j)                                               \
      pfa[j] = *(const i32x4*)(aP + (size_t)j * 32 * K_DIM + (k0));           \
    _Pragma("unroll")                                                         \
    for (int j = 0; j < 4; ++j)                                               \
      pfb[j] = *(const i32x4*)(bP + (size_t)j * 32 * K_DIM + (k0));           \
  } while (0)
#define WRITE_TILES()                                                         \
  do {                                                                        \
    _Pragma("unroll")                                                         \
    for (int j = 0; j < 4; ++j)                                               \
      *(i32x4*)&As[j * 32 * BKB + ldsOff] = pfa[j];                           \
    _Pragma("unroll")                                                         \
    for (int j = 0; j < 4; ++j)                                               \
      *(i32x4*)&Bs[j * 32 * BKB + ldsOff] = pfb[j];                           \
  } while (0)

  i32x4 acc[4][4];
#pragma unroll
  for (int i = 0; i < 4; ++i)
#pragma unroll
    for (int j = 0; j < 4; ++j)
      acc[i][j] = i32x4{0, 0, 0, 0};

  // prologue: stage tile 0
  LOAD_TILES(0);
  WRITE_TILES();
  __syncthreads();

  for (int kt = 0; kt < NT; ++kt) {
    // issue prefetch of tile kt+1 (clamped on last iter -> harmless re-read)
    const int kn = (kt + 1 < NT) ? (kt + 1) * BKB : kt * BKB;
    LOAD_TILES(kn);

    // compute on tile kt (LDS) — prefetch loads fly during this phase
#pragma unroll
    for (int kk = 0; kk < 2; ++kk) {
      i32x4 af[4], bq[4];
#pragma unroll
      for (int f = 0; f < 4; ++f) {
        const int pk = ((kk * 4 + quad) ^ (r & 7)) * 16;  // swizzled phys 16B group
        const int ml = wm * 64 + f * 16 + r;              // ml&7 == r&7
        af[f] = *(const i32x4*)&As[ml * BKB + pk];
        const int nl = wn * 64 + f * 16 + r;
        bq[f] = *(const i32x4*)&Bs[nl * BKB + pk];
      }
#pragma unroll
      for (int mf = 0; mf < 4; ++mf)
#pragma unroll
        for (int nf = 0; nf < 4; ++nf)
          acc[mf][nf] = __builtin_amdgcn_mfma_i32_16x16x64_i8(af[mf], bq[nf], acc[mf][nf], 0, 0, 0);
    }

    __syncthreads();   // all waves done reading; vmcnt drain cheap (loads landed)
    WRITE_TILES();     // stage tile kt+1 into LDS
    __syncthreads();   // LDS valid for next compute
  }

  // epilogue: t = s_a[row]*s_w*idot; out = sign(t)*|t|^(1/a); a==0.5 -> t*|t|
  const float a = alpha[0];
  const bool simple = (a == 0.5f);
  const float inv_a = 1.0f / a;
  const float sw = s_w[0];
#pragma unroll
  for (int mf = 0; mf < 4; ++mf) {
    const int gmb = m0 + wm * 64 + mf * 16 + quad * 4;
    float sa[4];
#pragma unroll
    for (int v = 0; v < 4; ++v) sa[v] = s_a[gmb + v] * sw;
#pragma unroll
    for (int nf = 0; nf < 4; ++nf) {
      const int gn = n0 + wn * 64 + nf * 16 + r;
      float* cp = C + (size_t)gmb * N_DIM + gn;
#pragma unroll
      for (int v = 0; v < 4; ++v) {
        float t = (float)acc[mf][nf][v] * sa[v];
        cp[(size_t)v * N_DIM] = simple ? t * fabsf(t)
                                       : copysignf(powf(fabsf(t), inv_a), t);
      }
    }
  }
#undef LOAD_TILES
#undef WRITE_TILES
}

extern "C" void kernel_launch(void* const* d_in, const int* in_sizes, int n_in,
                              void* d_out, int out_size, void* d_ws, size_t ws_size,
                              hipStream_t stream) {
  const float* x     = (const float*)d_in[0];  // [16384, 2048] fp32
  const float* cent  = (const float*)d_in[1];  // [16] fp32
  const float* alpha = (const float*)d_in[2];  // [1] fp32
  const int*   Wq    = (const int*)d_in[3];    // [2048, 2048] int32
  float* out = (float*)d_out;                  // [16384, 2048] fp32

  // ws layout: xq int8 [M][K] (32 MiB) | wq8 int8 [N][K] (4 MiB) | s_a [M] f32 | s_w [1] f32
  char*  xq  = (char*)d_ws;
  char*  wq8 = xq + (size_t)M_DIM * K_DIM;
  float* s_a = (float*)(wq8 + (size_t)N_DIM * K_DIM);
  float* s_w = s_a + M_DIM;

  quant_x_kernel<<<M_DIM, 256, 0, stream>>>(x, alpha, xq, s_a);
  quant_w_kernel<<<(N_DIM * (size_t)K_DIM) / (256 * 8), 256, 0, stream>>>(Wq, cent, wq8, s_w);

  dim3 grid((M_DIM / BM) * (N_DIM / BN));  // 2048 blocks
  gemm_i8_kernel<<<grid, 256, 0, stream>>>((const unsigned char*)xq, (const unsigned char*)wq8,
                                           out, alpha, s_a, s_w);
}